// Round 1
// baseline (279.672 us; speedup 1.0000x reference)
//
#include <hip/hip_runtime.h>

// Problem constants (fixed by the reference):
//   B=32, C=256, H=64, W=64.  Positions = B*H*W = 131072.
//   Channel stride in memory = H*W = 4096 floats (16 KiB) -> strided c-loop,
//   but waves cover consecutive w so every load instruction is a contiguous
//   256 B segment.  Streaming 268 MB total -> memory-bound, floor ~43 us.

#define BB   32
#define CC   256
#define HH   64
#define WW   64
#define HWSZ (HH * WW)          // 4096
#define NPOS (BB * HWSZ)        // 131072
#define SIM_EPS 1e-8f

__global__ __launch_bounds__(256) void
sim_reduce_kernel(const float* __restrict__ u,
                  const float* __restrict__ m,
                  const int* __restrict__ mask,
                  double* __restrict__ ws)
{
    const int p  = blockIdx.x * 256 + threadIdx.x;   // exactly covers NPOS
    const int b  = p >> 12;                          // p / 4096
    const int hw = p & (HWSZ - 1);                   // p % 4096

    const size_t base = (size_t)b * CC * HWSZ + hw;
    const float* up = u + base;
    const float* mp = m + base;

    float num = 0.f, uu = 0.f, mm = 0.f;
#pragma unroll 8
    for (int c = 0; c < CC; ++c) {
        const float a  = up[(size_t)c * HWSZ];
        const float bv = mp[(size_t)c * HWSZ];
        num = fmaf(a, bv, num);
        uu  = fmaf(a, a,  uu);
        mm  = fmaf(bv, bv, mm);
    }

    const float denom = fmaxf(sqrtf(uu), SIM_EPS) * fmaxf(sqrtf(mm), SIM_EPS);
    const float sim   = num / denom;

    const int mk = (mask[p] != 0) ? 1 : 0;
    double sd = mk ? (double)sim : 0.0;
    double md = (double)mk;

    // Wave-64 butterfly-free down-reduction.
#pragma unroll
    for (int off = 32; off > 0; off >>= 1) {
        sd += __shfl_down(sd, off, 64);
        md += __shfl_down(md, off, 64);
    }

    __shared__ double lds_s[4];
    __shared__ double lds_m[4];
    const int wave = threadIdx.x >> 6;
    const int lane = threadIdx.x & 63;
    if (lane == 0) { lds_s[wave] = sd; lds_m[wave] = md; }
    __syncthreads();

    if (threadIdx.x == 0) {
        const double ts = lds_s[0] + lds_s[1] + lds_s[2] + lds_s[3];
        const double tm = lds_m[0] + lds_m[1] + lds_m[2] + lds_m[3];
        atomicAdd(&ws[0], ts);   // device-scope by default on CDNA
        atomicAdd(&ws[1], tm);
    }
}

__global__ void finalize_kernel(const double* __restrict__ ws,
                                float* __restrict__ out)
{
    out[0] = (float)(ws[0] / ws[1]);
}

extern "C" void kernel_launch(void* const* d_in, const int* in_sizes, int n_in,
                              void* d_out, int out_size, void* d_ws, size_t ws_size,
                              hipStream_t stream)
{
    const float* u    = (const float*)d_in[0];
    const float* m    = (const float*)d_in[1];
    const int*   mask = (const int*)d_in[2];
    float*  out = (float*)d_out;
    double* ws  = (double*)d_ws;

    // ws is re-poisoned to 0xAA before every timed launch -> zero it on-stream
    // (async memset is graph-capture safe).
    hipMemsetAsync(d_ws, 0, 2 * sizeof(double), stream);

    sim_reduce_kernel<<<NPOS / 256, 256, 0, stream>>>(u, m, mask, ws);
    finalize_kernel<<<1, 1, 0, stream>>>(ws, out);
}